// Round 19
// baseline (306.105 us; speedup 1.0000x reference)
//
#include <hip/hip_runtime.h>
#include <hip/hip_bf16.h>
#include <math.h>

#define THREADS 256
#define NBUCK 64    // replicated stats buckets
#define EPB 4096    // edges per block in bucket-sort passes
#define RSB_SHIFT 8 // 256 nodes per dst-bucket

__device__ __forceinline__ float lrelu02(float x) { return x >= 0.f ? x : 0.2f * x; }
__device__ __forceinline__ float b2f(__hip_bfloat16 v) { return __bfloat162float(v); }
__device__ __forceinline__ short f2bf_bits(float v) {
  __hip_bfloat16 hb = __float2bfloat16(v);
  return *reinterpret_cast<short*>(&hb);
}

using bf16x8 = __attribute__((ext_vector_type(8))) short;
using f32x4  = __attribute__((ext_vector_type(4))) float;

// ---- fat kernel: bucket-count || layer-1 transform || prep (zero + W transpose) ----
__global__ void count_tf1_k(const int* __restrict__ dstv, int* __restrict__ gcnt,
                            int E, int NBLK, int nbkt,
                            const float* __restrict__ x, const float* __restrict__ W1,
                            const float* __restrict__ aS, const float* __restrict__ aD,
                            __hip_bfloat16* __restrict__ h, float* __restrict__ als,
                            float* __restrict__ ald, int N, int nbNode,
                            const float* __restrict__ W2, const float* __restrict__ W3,
                            __hip_bfloat16* __restrict__ wt2, __hip_bfloat16* __restrict__ wt3,
                            int* __restrict__ offs, float* __restrict__ statsRep,
                            float* __restrict__ poolbuf, float* __restrict__ padA,
                            float* __restrict__ padB) {
  __shared__ int cnt[512];
  __shared__ float xs[4][12];
  int tid = threadIdx.x;
  if ((int)blockIdx.x < NBLK) {
    for (int i = tid; i < nbkt; i += THREADS) cnt[i] = 0;
    __syncthreads();
    int e0 = blockIdx.x * EPB;
    int e1 = e0 + EPB; if (e1 > E) e1 = E;
    for (int i = e0 + tid; i < e1; i += THREADS)
      atomicAdd(&cnt[__builtin_nontemporal_load(dstv + i) >> RSB_SHIFT], 1);
    __syncthreads();
    for (int i = tid; i < nbkt; i += THREADS)
      gcnt[(long long)i * NBLK + blockIdx.x] = cnt[i];
    return;
  }
  if ((int)blockIdx.x < NBLK + nbNode) {
    int wave = tid >> 6, lane = tid & 63;
    int n = (blockIdx.x - NBLK) * 4 + wave;
    if (n < N && lane < 12) xs[wave][lane] = x[(long long)n * 12 + lane];
    __syncthreads();
    if (n >= N) return;
    float acc = 0.f;
#pragma unroll
    for (int k = 0; k < 12; k++) acc += xs[wave][k] * W1[k * 64 + lane];
    h[(long long)n * 64 + lane] = __float2bfloat16(acc);
    float ts = acc * aS[lane], td = acc * aD[lane];
    for (int m = 1; m < 16; m <<= 1) {
      ts += __shfl_xor(ts, m, 64);
      td += __shfl_xor(td, m, 64);
    }
    if ((lane & 15) == 0) {
      int hh = lane >> 4;
      als[(long long)n * 4 + hh] = ts;
      ald[(long long)n * 4 + hh] = td;
    }
    return;
  }
  // prep blocks (32)
  int pb = blockIdx.x - NBLK - nbNode;
  int gtid = pb * THREADS + tid;
  int stride = 32 * THREADS;
  if (gtid == 0) offs[N] = E;
  for (int i = gtid; i < 3 * NBUCK * 128; i += stride) statsRep[i] = 0.f;
  for (int i = gtid; i < 4096; i += stride) {
    poolbuf[i] = 0.f;
    padA[i] = 0.f;
    padB[i] = 0.f;
    int n = i >> 6, k = i & 63;
    wt2[n * 64 + k] = __float2bfloat16(W2[k * 64 + n]);
    wt3[n * 64 + k] = __float2bfloat16(W3[k * 64 + n]);
  }
}

// ---- scan pass 1 (block-local exclusive scan + block sums) ----
__global__ void scan1_k(const int* __restrict__ in, int* __restrict__ out,
                        int* __restrict__ bsums, int L) {
  __shared__ int s[THREADS];
  int i = blockIdx.x * THREADS + threadIdx.x;
  int v = (i < L) ? in[i] : 0;
  s[threadIdx.x] = v;
  __syncthreads();
  for (int off = 1; off < THREADS; off <<= 1) {
    int t = (threadIdx.x >= off) ? s[threadIdx.x - off] : 0;
    __syncthreads();
    s[threadIdx.x] += t;
    __syncthreads();
  }
  if (i < L) out[i] = s[threadIdx.x] - v;
  if (threadIdx.x == THREADS - 1) bsums[blockIdx.x] = s[THREADS - 1];
}

// ---- scan pass 2+3 merged: each block computes its own bsums prefix (L2-hot) ----
__global__ void scan23_k(int* __restrict__ a, const int* __restrict__ bsums, int L) {
  __shared__ int s[THREADS];
  int tid = threadIdx.x, blk = blockIdx.x;
  int acc = 0;
  for (int i = tid; i < blk; i += THREADS) acc += bsums[i];
  s[tid] = acc;
  __syncthreads();
  for (int off = 128; off > 0; off >>= 1) {
    if (tid < off) s[tid] += s[tid + off];
    __syncthreads();
  }
  int prefix = s[0];
  int i = blk * THREADS + tid;
  if (i < L) a[i] += prefix;
}

// ---- bucket scatter: edges -> bucket-sorted binned (LDS cursors, packed u32) ----
__global__ void binscatter_k(const int* __restrict__ srcv, const int* __restrict__ dstv,
                             const int* __restrict__ gbase, unsigned int* __restrict__ binned,
                             int E, int NBLK, int nbkt) {
  __shared__ int cur[512];
  int tid = threadIdx.x;
  int blk = blockIdx.x;
  for (int i = tid; i < nbkt; i += THREADS) cur[i] = gbase[(long long)i * NBLK + blk];
  __syncthreads();
  int e0 = blk * EPB;
  int e1 = e0 + EPB; if (e1 > E) e1 = E;
  for (int i = e0 + tid; i < e1; i += THREADS) {
    int d = __builtin_nontemporal_load(dstv + i);
    int s = __builtin_nontemporal_load(srcv + i);
    int p = atomicAdd(&cur[d >> RSB_SHIFT], 1);  // LDS atomic
    binned[p] = ((unsigned)s << 8) | (unsigned)(d & 255);
  }
}

// ---- per-bucket CSR: count + scan + scatter, all in LDS ----
__global__ void bucket_csr_k(const unsigned int* __restrict__ binned,
                             const int* __restrict__ gbase,
                             int* __restrict__ offs, int* __restrict__ csr,
                             int N, int E, int NBLK, int nbkt) {
  __shared__ int lcnt[256];
  __shared__ int lofs[256];
  int b = blockIdx.x;
  int lo = b << RSB_SHIFT;
  int tid = threadIdx.x;
  int b0 = gbase[(long long)b * NBLK];
  int b1 = (b + 1 < nbkt) ? gbase[(long long)(b + 1) * NBLK] : E;
  lcnt[tid] = 0;
  __syncthreads();
  for (int i = b0 + tid; i < b1; i += THREADS)
    atomicAdd(&lcnt[binned[i] & 255u], 1);
  __syncthreads();
  int v = lcnt[tid];
  lofs[tid] = v;
  __syncthreads();
  for (int off = 1; off < 256; off <<= 1) {
    int t = (tid >= off) ? lofs[tid - off] : 0;
    __syncthreads();
    lofs[tid] += t;
    __syncthreads();
  }
  int excl = lofs[tid] - v;
  int node = lo + tid;
  if (node < N) offs[node] = b0 + excl;
  lcnt[tid] = excl;
  __syncthreads();
  for (int i = b0 + tid; i < b1; i += THREADS) {
    unsigned e = binned[i];
    int r = atomicAdd(&lcnt[e & 255u], 1);  // LDS atomic
    csr[b0 + r] = (int)(e >> 8);
  }
}

// ---- inline BN finalize: statsRep -> sscS (scale | shift) ----
__device__ __forceinline__ void compute_ssc(const float* __restrict__ rep,
                                            const float* __restrict__ g,
                                            const float* __restrict__ be,
                                            float* sscS, int N) {
  int tid = threadIdx.x;
  if (tid < 128) {
    float a = 0.f;
#pragma unroll 8
    for (int b = 0; b < NBUCK; b++) a += rep[b * 128 + tid];
    sscS[tid] = a;
  }
  __syncthreads();
  if (tid < 64) {
    float inv = 1.f / (float)N;
    float mu = sscS[tid] * inv;
    float var = sscS[64 + tid] * inv - mu * mu;
    float sc = rsqrtf(var + 1e-5f) * g[tid];
    sscS[tid] = sc;
    sscS[64 + tid] = be[tid] - mu * sc;
  }
  __syncthreads();
}

// ---- MFMA transform, fused BN(inline stats)+ELU+cast ----
template <int H>
__global__ __launch_bounds__(256) void transform_mfma(
    const float* __restrict__ pre, const float* __restrict__ statsRep,
    const float* __restrict__ g0, const float* __restrict__ be0,
    const __hip_bfloat16* __restrict__ wt,
    const float* __restrict__ aS, const float* __restrict__ aD,
    __hip_bfloat16* __restrict__ h, float* __restrict__ als, float* __restrict__ ald,
    int N) {
  __shared__ float sscS[128];
  compute_ssc(statsRep, g0, be0, sscS, N);
  int wid = threadIdx.x >> 6, lane = threadIdx.x & 63;
  int m0 = blockIdx.x * 64 + wid * 16;
  int r = lane & 15, g = lane >> 4;
  const float* arow = pre + (long long)(m0 + r) * 64;
  int k0 = g * 8;
  bf16x8 a0, a1;
#pragma unroll
  for (int i = 0; i < 8; i++) {
    int ka = k0 + i, kb = k0 + 32 + i;
    float va = arow[ka] * sscS[ka] + sscS[64 + ka];
    float vb = arow[kb] * sscS[kb] + sscS[64 + kb];
    va = va > 0.f ? va : (__expf(va) - 1.f);
    vb = vb > 0.f ? vb : (__expf(vb) - 1.f);
    a0[i] = f2bf_bits(va);
    a1[i] = f2bf_bits(vb);
  }
  f32x4 acc[4];
#pragma unroll
  for (int s = 0; s < 4; s++) acc[s] = (f32x4){0.f, 0.f, 0.f, 0.f};
#pragma unroll
  for (int s = 0; s < 4; s++) {
    const bf16x8* brow = (const bf16x8*)(wt + (s * 16 + r) * 64 + k0);
    acc[s] = __builtin_amdgcn_mfma_f32_16x16x32_bf16(a0, brow[0], acc[s], 0, 0, 0);
    acc[s] = __builtin_amdgcn_mfma_f32_16x16x32_bf16(a1, brow[4], acc[s], 0, 0, 0);
  }
  float asum[4] = {0.f, 0.f, 0.f, 0.f}, dsum[4] = {0.f, 0.f, 0.f, 0.f};
#pragma unroll
  for (int s = 0; s < 4; s++) {
    int n = s * 16 + r;
    float sv = aS[n], dv = aD[n];
    float ts[4], td[4];
#pragma unroll
    for (int j = 0; j < 4; j++) { ts[j] = acc[s][j] * sv; td[j] = acc[s][j] * dv; }
#pragma unroll
    for (int mk = 1; mk < 16; mk <<= 1) {
#pragma unroll
      for (int j = 0; j < 4; j++) {
        ts[j] += __shfl_xor(ts[j], mk, 64);
        td[j] += __shfl_xor(td[j], mk, 64);
      }
    }
#pragma unroll
    for (int j = 0; j < 4; j++) {
      int m = m0 + g * 4 + j;
      if (m < N) {
        h[(long long)m * 64 + n] = __float2bfloat16(acc[s][j]);
        if (H == 4) {
          if (r == 0) { als[m * 4 + s] = ts[j]; ald[m * 4 + s] = td[j]; }
        }
      }
      if (H == 1) { asum[j] += ts[j]; dsum[j] += td[j]; }
    }
  }
  if (H == 1 && r == 0) {
#pragma unroll
    for (int j = 0; j < 4; j++) {
      int m = m0 + g * 4 + j;
      if (m < N) { als[m] = asum[j]; ald[m] = dsum[j]; }
    }
  }
}

// ---- Attention gather, H=4, 1 node/wave, chunk-4 early-exit phase B ----
__global__ void gat_gather4(const __hip_bfloat16* __restrict__ h, const float* __restrict__ als,
                            const float* __restrict__ ald, const int* __restrict__ offs,
                            const int* __restrict__ csr, const float* __restrict__ bias,
                            float* __restrict__ pre, float* __restrict__ statsRep, int N) {
  int wid = threadIdx.x >> 6, lane = threadIdx.x & 63;
  int n = blockIdx.x * 4 + wid;
  bool active = n < N;
  int t = lane & 3;
  int e = lane >> 2;
  int hh = lane >> 4;
  __shared__ float red[4][128];

  float v = 0.f;
  if (active) {
    float aldt = ald[n * 4 + t];
    float exs = __expf(lrelu02(als[n * 4 + t] + aldt));
    float sacc = 0.f;
    float acc = 0.f;
    int e0 = offs[n], e1 = offs[n + 1];

    for (int t0 = e0; t0 < e1; t0 += 16) {
      int idx = t0 + e;
      bool act = idx < e1;
      int sn = act ? csr[idx] : 0;
      float ex = act ? __expf(lrelu02(als[sn * 4 + t] + aldt)) : 0.f;
      sacc += ex;
      int cnt = e1 - t0; if (cnt > 16) cnt = 16;
#pragma unroll
      for (int c = 0; c < 4; c++) {
        if (c * 4 >= cnt) break;  // wave-uniform early exit (avg degree 12.8 < 16)
#pragma unroll
        for (int jj = 0; jj < 4; jj++) {
          int j = c * 4 + jj;
          int sj = __builtin_amdgcn_readlane(sn, j << 2);
          float exj = __shfl(ex, (j << 2) + hh, 64);
          acc += b2f(h[(long long)sj * 64 + lane]) * exj;
        }
      }
    }
#pragma unroll
    for (int ms = 4; ms < 64; ms <<= 1) sacc += __shfl_xor(sacc, ms, 64);
    float s = sacc + exs;
    float exsb = __shfl(exs, hh, 64);
    float sb = __shfl(s, hh, 64);
    acc += b2f(h[(long long)n * 64 + lane]) * exsb;
    v = acc / (sb + 1e-16f) + bias[lane];
    pre[(long long)n * 64 + lane] = v;
  }
  red[wid][lane] = v;
  red[wid][64 + lane] = v * v;
  __syncthreads();
  if (threadIdx.x < 128) {
    float s4 = red[0][threadIdx.x] + red[1][threadIdx.x] + red[2][threadIdx.x] + red[3][threadIdx.x];
    atomicAdd(&statsRep[(blockIdx.x & (NBUCK - 1)) * 128 + threadIdx.x], s4);
  }
}

// ---- Attention gather, H=1, 1 node/wave (unchanged) ----
__global__ void gat_gather1(const __hip_bfloat16* __restrict__ h, const float* __restrict__ als,
                            const float* __restrict__ ald, const int* __restrict__ offs,
                            const int* __restrict__ csr, const float* __restrict__ bias,
                            float* __restrict__ pre, float* __restrict__ statsRep, int N) {
  int wid = threadIdx.x >> 6, lane = threadIdx.x & 63;
  int n = blockIdx.x * 4 + wid;
  bool active = n < N;
  __shared__ float red[4][128];

  float v = 0.f;
  if (active) {
    float aldn = ald[n];
    float exs = __expf(lrelu02(als[n] + aldn));
    float sacc = 0.f, acc = 0.f;
    int e0 = offs[n], e1 = offs[n + 1];

    for (int t0 = e0; t0 < e1; t0 += 64) {
      int idx = t0 + lane;
      bool act = idx < e1;
      int sn = act ? csr[idx] : 0;
      float ex = act ? __expf(lrelu02(als[sn] + aldn)) : 0.f;
      sacc += ex;
      int cnt = e1 - t0;
#pragma unroll
      for (int c = 0; c < 4; c++) {
        if (c * 16 >= cnt) break;  // wave-uniform
#pragma unroll
        for (int j = 0; j < 16; j++) {
          int ln = c * 16 + j;
          int sj = __builtin_amdgcn_readlane(sn, ln);
          float exj = __int_as_float(__builtin_amdgcn_readlane(__float_as_int(ex), ln));
          acc += b2f(h[(long long)sj * 64 + lane]) * exj;
        }
      }
    }
#pragma unroll
    for (int ms = 1; ms < 64; ms <<= 1) sacc += __shfl_xor(sacc, ms, 64);
    float s = sacc + exs;
    acc += b2f(h[(long long)n * 64 + lane]) * exs;
    v = acc / (s + 1e-16f) + bias[lane];
    pre[(long long)n * 64 + lane] = v;
  }
  red[wid][lane] = v;
  red[wid][64 + lane] = v * v;
  __syncthreads();
  if (threadIdx.x < 128) {
    float s4 = red[0][threadIdx.x] + red[1][threadIdx.x] + red[2][threadIdx.x] + red[3][threadIdx.x];
    atomicAdd(&statsRep[(blockIdx.x & (NBUCK - 1)) * 128 + threadIdx.x], s4);
  }
}

// ---- fused: inline BN + nemb = elu(bn(pre3)) + pool partials ----
__global__ void emb_pool_k(const float* __restrict__ pre, const float* __restrict__ statsRep,
                           const float* __restrict__ g0, const float* __restrict__ be0,
                           const int* __restrict__ batch, float* __restrict__ nemb,
                           float* __restrict__ pool, int N, int per) {
  __shared__ float sscS[128];
  compute_ssc(statsRep, g0, be0, sscS, N);
  int lane = threadIdx.x & 63, wid = threadIdx.x >> 6;
  int gw = blockIdx.x * 4 + wid;
  int n0 = gw * per;
  int n1 = n0 + per; if (n1 > N) n1 = N;
  if (n0 >= n1) return;
  float sc = sscS[lane], sh = sscS[64 + lane];
  float acc = 0.f;
  int cg0 = batch[n0];
  for (int n = n0; n < n1; n++) {
    int g = batch[n];
    if (g != cg0) { atomicAdd(&pool[cg0 * 64 + lane], acc); acc = 0.f; cg0 = g; }
    float v = pre[(long long)n * 64 + lane] * sc + sh;
    v = v > 0.f ? v : (__expf(v) - 1.f);
    nemb[(long long)n * 64 + lane] = v;
    acc += v;
  }
  atomicAdd(&pool[cg0 * 64 + lane], acc);
}

// ---- classifier + embedding head, one block per graph ----
__global__ void head_k(const float* __restrict__ pool, const int* __restrict__ batch,
                       const float* __restrict__ Wc1, const float* __restrict__ bc1,
                       const float* __restrict__ Wc2, const float* __restrict__ bc2,
                       const float* __restrict__ We, const float* __restrict__ bee,
                       float* __restrict__ logits, float* __restrict__ emb, int N) {
  int g = blockIdx.x, lane = threadIdx.x;  // 64 threads
  __shared__ float pr[64], hid[32];
  __shared__ int bnds[2];
  if (lane < 2) {
    int target = g + lane;
    int lo = 0, hi = N;
    while (lo < hi) {
      int mid = (lo + hi) >> 1;
      if (batch[mid] < target) lo = mid + 1; else hi = mid;
    }
    bnds[lane] = lo;
  }
  __syncthreads();
  float cnt = (float)(bnds[1] - bnds[0]);
  pr[lane] = pool[g * 64 + lane] / fmaxf(cnt, 1.f);
  __syncthreads();
  if (lane < 32) {
    float a = bc1[lane];
    for (int k = 0; k < 64; k++) a += pr[k] * Wc1[k * 32 + lane];
    hid[lane] = fmaxf(a, 0.f);
  }
  float e = bee[lane];
  for (int k = 0; k < 64; k++) e += pr[k] * We[k * 64 + lane];
  emb[g * 64 + lane] = e;
  __syncthreads();
  if (lane < 2) {
    float l = bc2[lane];
    for (int k = 0; k < 32; k++) l += hid[k] * Wc2[k * 2 + lane];
    logits[g * 2 + lane] = l;
  }
}

extern "C" void kernel_launch(void* const* d_in, const int* in_sizes, int n_in,
                              void* d_out, int out_size, void* d_ws, size_t ws_size,
                              hipStream_t stream) {
  const float* x    = (const float*)d_in[0];
  const int*   ei   = (const int*)d_in[1];
  const int*   batch= (const int*)d_in[2];
  const float* W1   = (const float*)d_in[3];
  const float* as1  = (const float*)d_in[4];
  const float* ad1  = (const float*)d_in[5];
  const float* b1   = (const float*)d_in[6];
  const float* g1   = (const float*)d_in[7];
  const float* be1  = (const float*)d_in[8];
  const float* W2   = (const float*)d_in[9];
  const float* as2  = (const float*)d_in[10];
  const float* ad2  = (const float*)d_in[11];
  const float* b2   = (const float*)d_in[12];
  const float* g2   = (const float*)d_in[13];
  const float* be2  = (const float*)d_in[14];
  const float* W3   = (const float*)d_in[15];
  const float* as3  = (const float*)d_in[16];
  const float* ad3  = (const float*)d_in[17];
  const float* b3   = (const float*)d_in[18];
  const float* g3   = (const float*)d_in[19];
  const float* be3  = (const float*)d_in[20];
  const float* Wc1  = (const float*)d_in[21];
  const float* bc1  = (const float*)d_in[22];
  const float* Wc2  = (const float*)d_in[23];
  const float* bc2  = (const float*)d_in[24];
  const float* We   = (const float*)d_in[25];
  const float* bee  = (const float*)d_in[26];

  int N = in_sizes[0] / 12;
  int E = in_sizes[1] / 2;
  const int* srcv = ei;
  const int* dstv = ei + E;

  char* p = (char*)d_ws;
  auto carve = [&](size_t bytes) -> char* {
    char* r = p;
    p += (bytes + 255) & ~(size_t)255;
    return r;
  };
  int NBLK = (E + EPB - 1) / EPB;
  int nbkt = (N + 255) >> RSB_SHIFT;
  long long L = (long long)nbkt * NBLK;
  int Li = (int)L;
  int nbL = (Li + THREADS - 1) / THREADS;

  int* offs    = (int*)carve((size_t)(N + 1) * 4);
  int* gcnt    = (int*)carve((size_t)L * 4);
  int* gbase   = (int*)carve((size_t)L * 4);
  int* bsums   = (int*)carve(4096 * 4);
  int* csr     = (int*)carve((size_t)E * 4);
  unsigned int* binned = (unsigned int*)carve((size_t)E * 4);
  __hip_bfloat16* h  = (__hip_bfloat16*)carve((size_t)N * 64 * 2);
  __hip_bfloat16* wt2 = (__hip_bfloat16*)carve(64 * 64 * 2);
  __hip_bfloat16* wt3 = (__hip_bfloat16*)carve(64 * 64 * 2);
  float* als   = (float*)carve((size_t)N * 4 * 4);
  float* ald   = (float*)carve((size_t)N * 4 * 4);
  float* preA  = (float*)carve((size_t)(N + 64) * 64 * 4);
  float* preB  = (float*)carve((size_t)(N + 64) * 64 * 4);
  float* statsRep = (float*)carve(3 * NBUCK * 128 * 4);
  float* poolbuf  = (float*)carve(64 * 64 * 4);
  float* padA = preA + (size_t)N * 64;
  float* padB = preB + (size_t)N * 64;

  int nbNode = (N + 3) / 4;
  int nbT = (N + 63) / 64;

  // fat: bucket-count || layer-1 transform || prep
  count_tf1_k<<<NBLK + nbNode + 32, THREADS, 0, stream>>>(
      dstv, gcnt, E, NBLK, nbkt, x, W1, as1, ad1, h, als, ald, N, nbNode,
      W2, W3, wt2, wt3, offs, statsRep, poolbuf, padA, padB);
  // CSR build (separate dispatches; grid.sync measured 10x worse on MI355X)
  scan1_k<<<nbL, THREADS, 0, stream>>>(gcnt, gbase, bsums, Li);
  scan23_k<<<nbL, THREADS, 0, stream>>>(gbase, bsums, Li);
  binscatter_k<<<NBLK, THREADS, 0, stream>>>(srcv, dstv, gbase, binned, E, NBLK, nbkt);
  bucket_csr_k<<<nbkt, THREADS, 0, stream>>>(binned, gbase, offs, csr, N, E, NBLK, nbkt);

  // ---- layer 1 gather ----
  gat_gather4<<<nbNode, THREADS, 0, stream>>>(h, als, ald, offs, csr, b1, preA, statsRep, N);
  // ---- layer 2 (MFMA, inline BN) ----
  transform_mfma<4><<<nbT, THREADS, 0, stream>>>(preA, statsRep, g1, be1, wt2, as2, ad2, h, als, ald, N);
  gat_gather4<<<nbNode, THREADS, 0, stream>>>(h, als, ald, offs, csr, b2, preB, statsRep + NBUCK * 128, N);
  // ---- layer 3 (MFMA, inline BN) ----
  transform_mfma<1><<<nbT, THREADS, 0, stream>>>(preB, statsRep + NBUCK * 128, g2, be2, wt3, as3, ad3, h, als, ald, N);
  gat_gather1<<<nbNode, THREADS, 0, stream>>>(h, als, ald, offs, csr, b3, preA, statsRep + 2 * NBUCK * 128, N);

  float* outF   = (float*)d_out;
  float* logits = outF;
  float* emb    = outF + 64 * 2;
  float* nemb   = outF + 64 * 2 + 64 * 64;

  const int PER = 16;
  int nWaves = (N + PER - 1) / PER;
  int nbPool = (nWaves + 3) / 4;
  emb_pool_k<<<nbPool, THREADS, 0, stream>>>(preA, statsRep + 2 * NBUCK * 128, g3, be3,
                                             batch, nemb, poolbuf, N, PER);
  head_k<<<64, 64, 0, stream>>>(poolbuf, batch, Wc1, bc1, Wc2, bc2, We, bee, logits, emb, N);
}

// Round 20
// 290.058 us; speedup vs baseline: 1.0553x; 1.0553x over previous
//
#include <hip/hip_runtime.h>
#include <hip/hip_bf16.h>
#include <math.h>

#define THREADS 256
#define NBUCK 64    // replicated stats buckets
#define EPB 4096    // edges per block in bucket-sort passes
#define RSB_SHIFT 8 // 256 nodes per dst-bucket

__device__ __forceinline__ float lrelu02(float x) { return x >= 0.f ? x : 0.2f * x; }
__device__ __forceinline__ float b2f(__hip_bfloat16 v) { return __bfloat162float(v); }
__device__ __forceinline__ short f2bf_bits(float v) {
  __hip_bfloat16 hb = __float2bfloat16(v);
  return *reinterpret_cast<short*>(&hb);
}

using bf16x8 = __attribute__((ext_vector_type(8))) short;
using f32x4  = __attribute__((ext_vector_type(4))) float;

// ---- fat kernel: bucket-count || layer-1 transform || prep (zero + W transpose) ----
__global__ void count_tf1_k(const int* __restrict__ dstv, int* __restrict__ gcnt,
                            int E, int NBLK, int nbkt,
                            const float* __restrict__ x, const float* __restrict__ W1,
                            const float* __restrict__ aS, const float* __restrict__ aD,
                            __hip_bfloat16* __restrict__ h, float* __restrict__ als,
                            float* __restrict__ ald, int N, int nbNode,
                            const float* __restrict__ W2, const float* __restrict__ W3,
                            __hip_bfloat16* __restrict__ wt2, __hip_bfloat16* __restrict__ wt3,
                            int* __restrict__ offs, float* __restrict__ statsRep,
                            float* __restrict__ poolbuf, float* __restrict__ padA,
                            float* __restrict__ padB) {
  __shared__ int cnt[512];
  __shared__ float xs[4][12];
  int tid = threadIdx.x;
  if ((int)blockIdx.x < NBLK) {
    for (int i = tid; i < nbkt; i += THREADS) cnt[i] = 0;
    __syncthreads();
    int e0 = blockIdx.x * EPB;
    int e1 = e0 + EPB; if (e1 > E) e1 = E;
    for (int i = e0 + tid; i < e1; i += THREADS)
      atomicAdd(&cnt[__builtin_nontemporal_load(dstv + i) >> RSB_SHIFT], 1);
    __syncthreads();
    for (int i = tid; i < nbkt; i += THREADS)
      gcnt[(long long)i * NBLK + blockIdx.x] = cnt[i];
    return;
  }
  if ((int)blockIdx.x < NBLK + nbNode) {
    int wave = tid >> 6, lane = tid & 63;
    int n = (blockIdx.x - NBLK) * 4 + wave;
    if (n < N && lane < 12) xs[wave][lane] = x[(long long)n * 12 + lane];
    __syncthreads();
    if (n >= N) return;
    float acc = 0.f;
#pragma unroll
    for (int k = 0; k < 12; k++) acc += xs[wave][k] * W1[k * 64 + lane];
    h[(long long)n * 64 + lane] = __float2bfloat16(acc);
    float ts = acc * aS[lane], td = acc * aD[lane];
    for (int m = 1; m < 16; m <<= 1) {
      ts += __shfl_xor(ts, m, 64);
      td += __shfl_xor(td, m, 64);
    }
    if ((lane & 15) == 0) {
      int hh = lane >> 4;
      als[(long long)n * 4 + hh] = ts;
      ald[(long long)n * 4 + hh] = td;
    }
    return;
  }
  // prep blocks (32)
  int pb = blockIdx.x - NBLK - nbNode;
  int gtid = pb * THREADS + tid;
  int stride = 32 * THREADS;
  if (gtid == 0) offs[N] = E;
  for (int i = gtid; i < 3 * NBUCK * 128; i += stride) statsRep[i] = 0.f;
  for (int i = gtid; i < 4096; i += stride) {
    poolbuf[i] = 0.f;
    padA[i] = 0.f;
    padB[i] = 0.f;
    int n = i >> 6, k = i & 63;
    wt2[n * 64 + k] = __float2bfloat16(W2[k * 64 + n]);
    wt3[n * 64 + k] = __float2bfloat16(W3[k * 64 + n]);
  }
}

// ---- scan pass 1 (block-local exclusive scan + block sums) ----
__global__ void scan1_k(const int* __restrict__ in, int* __restrict__ out,
                        int* __restrict__ bsums, int L) {
  __shared__ int s[THREADS];
  int i = blockIdx.x * THREADS + threadIdx.x;
  int v = (i < L) ? in[i] : 0;
  s[threadIdx.x] = v;
  __syncthreads();
  for (int off = 1; off < THREADS; off <<= 1) {
    int t = (threadIdx.x >= off) ? s[threadIdx.x - off] : 0;
    __syncthreads();
    s[threadIdx.x] += t;
    __syncthreads();
  }
  if (i < L) out[i] = s[threadIdx.x] - v;
  if (threadIdx.x == THREADS - 1) bsums[blockIdx.x] = s[THREADS - 1];
}

// ---- scan pass 2+3 merged: each block computes its own bsums prefix (L2-hot) ----
__global__ void scan23_k(int* __restrict__ a, const int* __restrict__ bsums, int L) {
  __shared__ int s[THREADS];
  int tid = threadIdx.x, blk = blockIdx.x;
  int acc = 0;
  for (int i = tid; i < blk; i += THREADS) acc += bsums[i];
  s[tid] = acc;
  __syncthreads();
  for (int off = 128; off > 0; off >>= 1) {
    if (tid < off) s[tid] += s[tid + off];
    __syncthreads();
  }
  int prefix = s[0];
  int i = blk * THREADS + tid;
  if (i < L) a[i] += prefix;
}

// ---- bucket scatter: edges -> bucket-sorted binned (LDS cursors, packed u32) ----
__global__ void binscatter_k(const int* __restrict__ srcv, const int* __restrict__ dstv,
                             const int* __restrict__ gbase, unsigned int* __restrict__ binned,
                             int E, int NBLK, int nbkt) {
  __shared__ int cur[512];
  int tid = threadIdx.x;
  int blk = blockIdx.x;
  for (int i = tid; i < nbkt; i += THREADS) cur[i] = gbase[(long long)i * NBLK + blk];
  __syncthreads();
  int e0 = blk * EPB;
  int e1 = e0 + EPB; if (e1 > E) e1 = E;
  for (int i = e0 + tid; i < e1; i += THREADS) {
    int d = __builtin_nontemporal_load(dstv + i);
    int s = __builtin_nontemporal_load(srcv + i);
    int p = atomicAdd(&cur[d >> RSB_SHIFT], 1);  // LDS atomic
    binned[p] = ((unsigned)s << 8) | (unsigned)(d & 255);
  }
}

// ---- per-bucket CSR: count + scan + scatter, all in LDS ----
__global__ void bucket_csr_k(const unsigned int* __restrict__ binned,
                             const int* __restrict__ gbase,
                             int* __restrict__ offs, int* __restrict__ csr,
                             int N, int E, int NBLK, int nbkt) {
  __shared__ int lcnt[256];
  __shared__ int lofs[256];
  int b = blockIdx.x;
  int lo = b << RSB_SHIFT;
  int tid = threadIdx.x;
  int b0 = gbase[(long long)b * NBLK];
  int b1 = (b + 1 < nbkt) ? gbase[(long long)(b + 1) * NBLK] : E;
  lcnt[tid] = 0;
  __syncthreads();
  for (int i = b0 + tid; i < b1; i += THREADS)
    atomicAdd(&lcnt[binned[i] & 255u], 1);
  __syncthreads();
  int v = lcnt[tid];
  lofs[tid] = v;
  __syncthreads();
  for (int off = 1; off < 256; off <<= 1) {
    int t = (tid >= off) ? lofs[tid - off] : 0;
    __syncthreads();
    lofs[tid] += t;
    __syncthreads();
  }
  int excl = lofs[tid] - v;
  int node = lo + tid;
  if (node < N) offs[node] = b0 + excl;
  lcnt[tid] = excl;
  __syncthreads();
  for (int i = b0 + tid; i < b1; i += THREADS) {
    unsigned e = binned[i];
    int r = atomicAdd(&lcnt[e & 255u], 1);  // LDS atomic
    csr[b0 + r] = (int)(e >> 8);
  }
}

// ---- inline BN finalize: statsRep -> sscS (scale | shift) ----
__device__ __forceinline__ void compute_ssc(const float* __restrict__ rep,
                                            const float* __restrict__ g,
                                            const float* __restrict__ be,
                                            float* sscS, int N) {
  int tid = threadIdx.x;
  if (tid < 128) {
    float a = 0.f;
#pragma unroll 8
    for (int b = 0; b < NBUCK; b++) a += rep[b * 128 + tid];
    sscS[tid] = a;
  }
  __syncthreads();
  if (tid < 64) {
    float inv = 1.f / (float)N;
    float mu = sscS[tid] * inv;
    float var = sscS[64 + tid] * inv - mu * mu;
    float sc = rsqrtf(var + 1e-5f) * g[tid];
    sscS[tid] = sc;
    sscS[64 + tid] = be[tid] - mu * sc;
  }
  __syncthreads();
}

// ---- MFMA transform, fused BN(inline stats)+ELU+cast ----
template <int H>
__global__ __launch_bounds__(256) void transform_mfma(
    const float* __restrict__ pre, const float* __restrict__ statsRep,
    const float* __restrict__ g0, const float* __restrict__ be0,
    const __hip_bfloat16* __restrict__ wt,
    const float* __restrict__ aS, const float* __restrict__ aD,
    __hip_bfloat16* __restrict__ h, float* __restrict__ als, float* __restrict__ ald,
    int N) {
  __shared__ float sscS[128];
  compute_ssc(statsRep, g0, be0, sscS, N);
  int wid = threadIdx.x >> 6, lane = threadIdx.x & 63;
  int m0 = blockIdx.x * 64 + wid * 16;
  int r = lane & 15, g = lane >> 4;
  const float* arow = pre + (long long)(m0 + r) * 64;
  int k0 = g * 8;
  bf16x8 a0, a1;
#pragma unroll
  for (int i = 0; i < 8; i++) {
    int ka = k0 + i, kb = k0 + 32 + i;
    float va = arow[ka] * sscS[ka] + sscS[64 + ka];
    float vb = arow[kb] * sscS[kb] + sscS[64 + kb];
    va = va > 0.f ? va : (__expf(va) - 1.f);
    vb = vb > 0.f ? vb : (__expf(vb) - 1.f);
    a0[i] = f2bf_bits(va);
    a1[i] = f2bf_bits(vb);
  }
  f32x4 acc[4];
#pragma unroll
  for (int s = 0; s < 4; s++) acc[s] = (f32x4){0.f, 0.f, 0.f, 0.f};
#pragma unroll
  for (int s = 0; s < 4; s++) {
    const bf16x8* brow = (const bf16x8*)(wt + (s * 16 + r) * 64 + k0);
    acc[s] = __builtin_amdgcn_mfma_f32_16x16x32_bf16(a0, brow[0], acc[s], 0, 0, 0);
    acc[s] = __builtin_amdgcn_mfma_f32_16x16x32_bf16(a1, brow[4], acc[s], 0, 0, 0);
  }
  float asum[4] = {0.f, 0.f, 0.f, 0.f}, dsum[4] = {0.f, 0.f, 0.f, 0.f};
#pragma unroll
  for (int s = 0; s < 4; s++) {
    int n = s * 16 + r;
    float sv = aS[n], dv = aD[n];
    float ts[4], td[4];
#pragma unroll
    for (int j = 0; j < 4; j++) { ts[j] = acc[s][j] * sv; td[j] = acc[s][j] * dv; }
#pragma unroll
    for (int mk = 1; mk < 16; mk <<= 1) {
#pragma unroll
      for (int j = 0; j < 4; j++) {
        ts[j] += __shfl_xor(ts[j], mk, 64);
        td[j] += __shfl_xor(td[j], mk, 64);
      }
    }
#pragma unroll
    for (int j = 0; j < 4; j++) {
      int m = m0 + g * 4 + j;
      if (m < N) {
        h[(long long)m * 64 + n] = __float2bfloat16(acc[s][j]);
        if (H == 4) {
          if (r == 0) { als[m * 4 + s] = ts[j]; ald[m * 4 + s] = td[j]; }
        }
      }
      if (H == 1) { asum[j] += ts[j]; dsum[j] += td[j]; }
    }
  }
  if (H == 1 && r == 0) {
#pragma unroll
    for (int j = 0; j < 4; j++) {
      int m = m0 + g * 4 + j;
      if (m < N) { als[m] = asum[j]; ald[m] = dsum[j]; }
    }
  }
}

// ---- Attention gather, H=4, 1 node/wave, full-16 unrolled phase B (max MLP) ----
__global__ void gat_gather4(const __hip_bfloat16* __restrict__ h, const float* __restrict__ als,
                            const float* __restrict__ ald, const int* __restrict__ offs,
                            const int* __restrict__ csr, const float* __restrict__ bias,
                            float* __restrict__ pre, float* __restrict__ statsRep, int N) {
  int wid = threadIdx.x >> 6, lane = threadIdx.x & 63;
  int n = blockIdx.x * 4 + wid;
  bool active = n < N;
  int t = lane & 3;
  int e = lane >> 2;
  int hh = lane >> 4;
  __shared__ float red[4][128];

  float v = 0.f;
  if (active) {
    float aldt = ald[n * 4 + t];
    float exs = __expf(lrelu02(als[n * 4 + t] + aldt));
    float sacc = 0.f;
    float acc = 0.f;
    int e0 = offs[n], e1 = offs[n + 1];

    for (int t0 = e0; t0 < e1; t0 += 16) {
      int idx = t0 + e;
      bool act = idx < e1;
      int sn = act ? csr[idx] : 0;
      float ex = act ? __expf(lrelu02(als[sn * 4 + t] + aldt)) : 0.f;
      sacc += ex;
#pragma unroll
      for (int j = 0; j < 16; j++) {
        int sj = __builtin_amdgcn_readlane(sn, j << 2);
        float exj = __shfl(ex, (j << 2) + hh, 64);
        acc += b2f(h[(long long)sj * 64 + lane]) * exj;
      }
    }
#pragma unroll
    for (int ms = 4; ms < 64; ms <<= 1) sacc += __shfl_xor(sacc, ms, 64);
    float s = sacc + exs;
    float exsb = __shfl(exs, hh, 64);
    float sb = __shfl(s, hh, 64);
    acc += b2f(h[(long long)n * 64 + lane]) * exsb;
    v = acc / (sb + 1e-16f) + bias[lane];
    pre[(long long)n * 64 + lane] = v;
  }
  red[wid][lane] = v;
  red[wid][64 + lane] = v * v;
  __syncthreads();
  if (threadIdx.x < 128) {
    float s4 = red[0][threadIdx.x] + red[1][threadIdx.x] + red[2][threadIdx.x] + red[3][threadIdx.x];
    atomicAdd(&statsRep[(blockIdx.x & (NBUCK - 1)) * 128 + threadIdx.x], s4);
  }
}

// ---- Attention gather, H=1, 1 node/wave ----
__global__ void gat_gather1(const __hip_bfloat16* __restrict__ h, const float* __restrict__ als,
                            const float* __restrict__ ald, const int* __restrict__ offs,
                            const int* __restrict__ csr, const float* __restrict__ bias,
                            float* __restrict__ pre, float* __restrict__ statsRep, int N) {
  int wid = threadIdx.x >> 6, lane = threadIdx.x & 63;
  int n = blockIdx.x * 4 + wid;
  bool active = n < N;
  __shared__ float red[4][128];

  float v = 0.f;
  if (active) {
    float aldn = ald[n];
    float exs = __expf(lrelu02(als[n] + aldn));
    float sacc = 0.f, acc = 0.f;
    int e0 = offs[n], e1 = offs[n + 1];

    for (int t0 = e0; t0 < e1; t0 += 64) {
      int idx = t0 + lane;
      bool act = idx < e1;
      int sn = act ? csr[idx] : 0;
      float ex = act ? __expf(lrelu02(als[sn] + aldn)) : 0.f;
      sacc += ex;
      int cnt = e1 - t0;
#pragma unroll
      for (int c = 0; c < 4; c++) {
        if (c * 16 >= cnt) break;  // wave-uniform
#pragma unroll
        for (int j = 0; j < 16; j++) {
          int ln = c * 16 + j;
          int sj = __builtin_amdgcn_readlane(sn, ln);
          float exj = __int_as_float(__builtin_amdgcn_readlane(__float_as_int(ex), ln));
          acc += b2f(h[(long long)sj * 64 + lane]) * exj;
        }
      }
    }
#pragma unroll
    for (int ms = 1; ms < 64; ms <<= 1) sacc += __shfl_xor(sacc, ms, 64);
    float s = sacc + exs;
    acc += b2f(h[(long long)n * 64 + lane]) * exs;
    v = acc / (s + 1e-16f) + bias[lane];
    pre[(long long)n * 64 + lane] = v;
  }
  red[wid][lane] = v;
  red[wid][64 + lane] = v * v;
  __syncthreads();
  if (threadIdx.x < 128) {
    float s4 = red[0][threadIdx.x] + red[1][threadIdx.x] + red[2][threadIdx.x] + red[3][threadIdx.x];
    atomicAdd(&statsRep[(blockIdx.x & (NBUCK - 1)) * 128 + threadIdx.x], s4);
  }
}

// ---- fused: inline BN + nemb = elu(bn(pre3)) + pool partials ----
__global__ void emb_pool_k(const float* __restrict__ pre, const float* __restrict__ statsRep,
                           const float* __restrict__ g0, const float* __restrict__ be0,
                           const int* __restrict__ batch, float* __restrict__ nemb,
                           float* __restrict__ pool, int N, int per) {
  __shared__ float sscS[128];
  compute_ssc(statsRep, g0, be0, sscS, N);
  int lane = threadIdx.x & 63, wid = threadIdx.x >> 6;
  int gw = blockIdx.x * 4 + wid;
  int n0 = gw * per;
  int n1 = n0 + per; if (n1 > N) n1 = N;
  if (n0 >= n1) return;
  float sc = sscS[lane], sh = sscS[64 + lane];
  float acc = 0.f;
  int cg0 = batch[n0];
  for (int n = n0; n < n1; n++) {
    int g = batch[n];
    if (g != cg0) { atomicAdd(&pool[cg0 * 64 + lane], acc); acc = 0.f; cg0 = g; }
    float v = pre[(long long)n * 64 + lane] * sc + sh;
    v = v > 0.f ? v : (__expf(v) - 1.f);
    nemb[(long long)n * 64 + lane] = v;
    acc += v;
  }
  atomicAdd(&pool[cg0 * 64 + lane], acc);
}

// ---- classifier + embedding head, one block per graph ----
__global__ void head_k(const float* __restrict__ pool, const int* __restrict__ batch,
                       const float* __restrict__ Wc1, const float* __restrict__ bc1,
                       const float* __restrict__ Wc2, const float* __restrict__ bc2,
                       const float* __restrict__ We, const float* __restrict__ bee,
                       float* __restrict__ logits, float* __restrict__ emb, int N) {
  int g = blockIdx.x, lane = threadIdx.x;  // 64 threads
  __shared__ float pr[64], hid[32];
  __shared__ int bnds[2];
  if (lane < 2) {
    int target = g + lane;
    int lo = 0, hi = N;
    while (lo < hi) {
      int mid = (lo + hi) >> 1;
      if (batch[mid] < target) lo = mid + 1; else hi = mid;
    }
    bnds[lane] = lo;
  }
  __syncthreads();
  float cnt = (float)(bnds[1] - bnds[0]);
  pr[lane] = pool[g * 64 + lane] / fmaxf(cnt, 1.f);
  __syncthreads();
  if (lane < 32) {
    float a = bc1[lane];
    for (int k = 0; k < 64; k++) a += pr[k] * Wc1[k * 32 + lane];
    hid[lane] = fmaxf(a, 0.f);
  }
  float e = bee[lane];
  for (int k = 0; k < 64; k++) e += pr[k] * We[k * 64 + lane];
  emb[g * 64 + lane] = e;
  __syncthreads();
  if (lane < 2) {
    float l = bc2[lane];
    for (int k = 0; k < 32; k++) l += hid[k] * Wc2[k * 2 + lane];
    logits[g * 2 + lane] = l;
  }
}

extern "C" void kernel_launch(void* const* d_in, const int* in_sizes, int n_in,
                              void* d_out, int out_size, void* d_ws, size_t ws_size,
                              hipStream_t stream) {
  const float* x    = (const float*)d_in[0];
  const int*   ei   = (const int*)d_in[1];
  const int*   batch= (const int*)d_in[2];
  const float* W1   = (const float*)d_in[3];
  const float* as1  = (const float*)d_in[4];
  const float* ad1  = (const float*)d_in[5];
  const float* b1   = (const float*)d_in[6];
  const float* g1   = (const float*)d_in[7];
  const float* be1  = (const float*)d_in[8];
  const float* W2   = (const float*)d_in[9];
  const float* as2  = (const float*)d_in[10];
  const float* ad2  = (const float*)d_in[11];
  const float* b2   = (const float*)d_in[12];
  const float* g2   = (const float*)d_in[13];
  const float* be2  = (const float*)d_in[14];
  const float* W3   = (const float*)d_in[15];
  const float* as3  = (const float*)d_in[16];
  const float* ad3  = (const float*)d_in[17];
  const float* b3   = (const float*)d_in[18];
  const float* g3   = (const float*)d_in[19];
  const float* be3  = (const float*)d_in[20];
  const float* Wc1  = (const float*)d_in[21];
  const float* bc1  = (const float*)d_in[22];
  const float* Wc2  = (const float*)d_in[23];
  const float* bc2  = (const float*)d_in[24];
  const float* We   = (const float*)d_in[25];
  const float* bee  = (const float*)d_in[26];

  int N = in_sizes[0] / 12;
  int E = in_sizes[1] / 2;
  const int* srcv = ei;
  const int* dstv = ei + E;

  char* p = (char*)d_ws;
  auto carve = [&](size_t bytes) -> char* {
    char* r = p;
    p += (bytes + 255) & ~(size_t)255;
    return r;
  };
  int NBLK = (E + EPB - 1) / EPB;
  int nbkt = (N + 255) >> RSB_SHIFT;
  long long L = (long long)nbkt * NBLK;
  int Li = (int)L;
  int nbL = (Li + THREADS - 1) / THREADS;

  int* offs    = (int*)carve((size_t)(N + 1) * 4);
  int* gcnt    = (int*)carve((size_t)L * 4);
  int* gbase   = (int*)carve((size_t)L * 4);
  int* bsums   = (int*)carve(4096 * 4);
  int* csr     = (int*)carve((size_t)E * 4);
  unsigned int* binned = (unsigned int*)carve((size_t)E * 4);
  __hip_bfloat16* h  = (__hip_bfloat16*)carve((size_t)N * 64 * 2);
  __hip_bfloat16* wt2 = (__hip_bfloat16*)carve(64 * 64 * 2);
  __hip_bfloat16* wt3 = (__hip_bfloat16*)carve(64 * 64 * 2);
  float* als   = (float*)carve((size_t)N * 4 * 4);
  float* ald   = (float*)carve((size_t)N * 4 * 4);
  float* preA  = (float*)carve((size_t)(N + 64) * 64 * 4);
  float* preB  = (float*)carve((size_t)(N + 64) * 64 * 4);
  float* statsRep = (float*)carve(3 * NBUCK * 128 * 4);
  float* poolbuf  = (float*)carve(64 * 64 * 4);
  float* padA = preA + (size_t)N * 64;
  float* padB = preB + (size_t)N * 64;

  int nbNode = (N + 3) / 4;
  int nbT = (N + 63) / 64;

  // fat: bucket-count || layer-1 transform || prep
  count_tf1_k<<<NBLK + nbNode + 32, THREADS, 0, stream>>>(
      dstv, gcnt, E, NBLK, nbkt, x, W1, as1, ad1, h, als, ald, N, nbNode,
      W2, W3, wt2, wt3, offs, statsRep, poolbuf, padA, padB);
  // CSR build (separate dispatches; grid.sync measured 10x worse on MI355X)
  scan1_k<<<nbL, THREADS, 0, stream>>>(gcnt, gbase, bsums, Li);
  scan23_k<<<nbL, THREADS, 0, stream>>>(gbase, bsums, Li);
  binscatter_k<<<NBLK, THREADS, 0, stream>>>(srcv, dstv, gbase, binned, E, NBLK, nbkt);
  bucket_csr_k<<<nbkt, THREADS, 0, stream>>>(binned, gbase, offs, csr, N, E, NBLK, nbkt);

  // ---- layer 1 gather ----
  gat_gather4<<<nbNode, THREADS, 0, stream>>>(h, als, ald, offs, csr, b1, preA, statsRep, N);
  // ---- layer 2 (MFMA, inline BN) ----
  transform_mfma<4><<<nbT, THREADS, 0, stream>>>(preA, statsRep, g1, be1, wt2, as2, ad2, h, als, ald, N);
  gat_gather4<<<nbNode, THREADS, 0, stream>>>(h, als, ald, offs, csr, b2, preB, statsRep + NBUCK * 128, N);
  // ---- layer 3 (MFMA, inline BN) ----
  transform_mfma<1><<<nbT, THREADS, 0, stream>>>(preB, statsRep + NBUCK * 128, g2, be2, wt3, as3, ad3, h, als, ald, N);
  gat_gather1<<<nbNode, THREADS, 0, stream>>>(h, als, ald, offs, csr, b3, preA, statsRep + 2 * NBUCK * 128, N);

  float* outF   = (float*)d_out;
  float* logits = outF;
  float* emb    = outF + 64 * 2;
  float* nemb   = outF + 64 * 2 + 64 * 64;

  const int PER = 16;
  int nWaves = (N + PER - 1) / PER;
  int nbPool = (nWaves + 3) / 4;
  emb_pool_k<<<nbPool, THREADS, 0, stream>>>(preA, statsRep + 2 * NBUCK * 128, g3, be3,
                                             batch, nemb, poolbuf, N, PER);
  head_k<<<64, 64, 0, stream>>>(poolbuf, batch, Wc1, bc1, Wc2, bc2, We, bee, logits, emb, N);
}